// Round 9
// baseline (259.963 us; speedup 1.0000x reference)
//
#include <hip/hip_runtime.h>
#include <hip/hip_cooperative_groups.h>
#include <math.h>

// Problem constants (from reference):
//   N=32, C=1, H=512, W=1024 -> HW = 524288 per batch row
//   SAMPLE_NUM = 5000 pairs per row -> 160000 pairs total
//   SIGMA = 0.03, ALPHA = 1.0, EPS = 1e-6, LOSS_WEIGHT = 1.0
#define SAMPLE_NUM 5000
#define HWSZ (512 * 1024)
#define SIGMA_F 0.03f
#define EPS_F 1e-6f
#define THREADS 1024
#define VBLK_PER_ROW 8
#define PAIRS_PER_VBLK 640           // 10 waves x 64 lanes
#define PK_OFF_BYTES 32768           // packed mask at ws+32768 (2 MB)

// R12 design notes:
//  - R9/R10/R11 nulls triangulate: pack impl (x3) and validity grid (x2)
//    changes all land within 1.4 us. The invariant is LAUNCH COUNT.
//    Fitted per-launch overhead ~8-10 us (R6->R7 +7.5, R7->R9 +4.1,
//    R3->R4 -2500 atomics +1 launch = -0.8). 4-launch pipeline returns
//    the 21.5 us bitmap win as boundary overhead. Structure, not kernels.
//  - Fix: ONE cooperative kernel (guide: harness supports
//    hipLaunchCooperativeKernel). 256 blocks x 1024 thr, 64 KB LDS ->
//    co-resident (1 blk/CU, 16/32 waves). Phase A: full-grid pack
//    (16 MB coalesced). grid.sync. Phase B: 8 blocks/row load packed
//    row->LDS, eval validity IN-REGISTER (no bitmap buffer), valid
//    lanes gather, block-reduce -> slot. grid.sync. Phase C: block 0
//    reduces 256 slots -> out. Deletes 3 kernel boundaries (~27 us).
//  - LDS reuse: sbm (64 KB mask bits) -> float scratch for reductions
//    after a __syncthreads (static 64 KB == sharedMemPerBlock).

namespace cg = cooperative_groups;

__device__ __forceinline__ unsigned pack16_bytes(uint4 v) {
  // 16 bool bytes -> 16 bits. ((u & 0x01010101)*0x01020408)>>24 puts the
  // 4 byte-LSBs at bits 0..3. Validated end-to-end R7/R9-R11 (absmax=0).
  const unsigned n0 = ((v.x & 0x01010101u) * 0x01020408u) >> 24;
  const unsigned n1 = ((v.y & 0x01010101u) * 0x01020408u) >> 24;
  const unsigned n2 = ((v.z & 0x01010101u) * 0x01020408u) >> 24;
  const unsigned n3 = ((v.w & 0x01010101u) * 0x01020408u) >> 24;
  return (n0 & 0xFu) | ((n1 & 0xFu) << 4) | ((n2 & 0xFu) << 8) |
         ((n3 & 0xFu) << 12);
}

__device__ __forceinline__ unsigned lsb4_i32(uint4 v) {
  return (v.x & 1u) | ((v.y & 1u) << 1) | ((v.z & 1u) << 2) |
         ((v.w & 1u) << 3);
}

__global__ void __launch_bounds__(THREADS)
ranking_loss_fused(const float* __restrict__ pred,
                   const float* __restrict__ targ,
                   const void* __restrict__ mask_raw,
                   const int* __restrict__ idxA,
                   const int* __restrict__ idxB,
                   unsigned long long* __restrict__ mpack64,
                   float* __restrict__ slots, float* __restrict__ out,
                   int total) {
  __shared__ unsigned int sbm[HWSZ / 32];  // 64 KB: row mask bits
  const int t = threadIdx.x;
  const int bid = blockIdx.x;
  const int nblocks = gridDim.x;
  const int rows = total / SAMPLE_NUM;          // 32
  const int words64 = rows * (HWSZ / 64);       // 262,144

  // Mask layout detection (thread-uniform). int32 bools: every word is 0/1.
  // Byte bools: uint32 view >1 with P=7/8 per word; 32 words -> P_err=8^-32.
  const unsigned int* mw = (const unsigned int*)mask_raw;
  bool mask_is_i32 = true;
  #pragma unroll
  for (int w = 0; w < 32; ++w) {
    if (mw[w] > 1u) mask_is_i32 = false;
  }

  // ---- Phase A: full-grid bit-pack (thread i: elements [64i,64i+64)) ----
  for (int i = bid * THREADS + t; i < words64; i += nblocks * THREADS) {
    unsigned long long r;
    if (!mask_is_i32) {
      const uint4* src = (const uint4*)mask_raw + (i * 4);
      const uint4 v0 = src[0];
      const uint4 v1 = src[1];
      const uint4 v2 = src[2];
      const uint4 v3 = src[3];
      r = (unsigned long long)pack16_bytes(v0) |
          ((unsigned long long)pack16_bytes(v1) << 16) |
          ((unsigned long long)pack16_bytes(v2) << 32) |
          ((unsigned long long)pack16_bytes(v3) << 48);
    } else {
      const uint4* src = (const uint4*)mask_raw + (i * 16);
      unsigned long long acc = 0ull;
      #pragma unroll
      for (int k = 0; k < 16; ++k) {
        acc |= (unsigned long long)lsb4_i32(src[k]) << (4 * k);
      }
      r = acc;
    }
    mpack64[i] = r;
  }

  cg::this_grid().sync();

  // ---- Phase B: 8 blocks/row; full packed row -> LDS; eval + gather ----
  const int n = bid >> 3;   // row
  const int sub = bid & 7;  // 640-pair slice
  {
    const uint4* src =
        (const uint4*)((const unsigned int*)mpack64 + n * (HWSZ / 32));
    uint4* dst = (uint4*)sbm;
    #pragma unroll
    for (int it = 0; it < 4; ++it) {
      dst[t + it * THREADS] = src[t + it * THREADS];
    }
  }
  __syncthreads();

  const float hi = 1.0f + SIGMA_F;
  const float lo = 1.0f / (1.0f + SIGMA_F);
  float eq_sum = 0.0f, uneq_sum = 0.0f, valid = 0.0f;
  const int lane = t & 63;
  const int wv = t >> 6;  // 0..15; waves 0..9 carry pairs
  const int il = sub * PAIRS_PER_VBLK + wv * 64 + lane;  // < 5120
  if (wv < 10 && il < SAMPLE_NUM) {
    const int i = n * SAMPLE_NUM + il;
    const int a = idxA[i];
    const int b = idxB[i];
    if ((sbm[a >> 5] >> (a & 31)) & (sbm[b >> 5] >> (b & 31)) & 1u) {
      const int base = n * HWSZ;  // < 16.8M, fits i32
      const int ia_off = base + a;
      const int ib_off = base + b;
      // The mandatory random traffic: 4 gathers for ~25% of lanes.
      const float tA = targ[ia_off];
      const float tB = targ[ib_off];
      const float iA = pred[ia_off];
      const float iB = pred[ib_off];

      valid = 1.0f;
      const float ratio = tA / (tB + EPS_F);  // targ in [0.1,10] -> safe
      if (ratio < hi && ratio > lo) {
        const float d = iA - iB;
        eq_sum = d * d;  // ALPHA == 1.0
      } else {
        const float label = (ratio >= hi) ? 1.0f : -1.0f;
        const float x = (iB - iA) * label;
        uneq_sum = (x > 20.0f) ? x : log1pf(expf(x));  // log1p(exp(x))
      }
    }
  }

  // Wave-64 shuffle reduction
  #pragma unroll
  for (int off = 32; off > 0; off >>= 1) {
    eq_sum   += __shfl_down(eq_sum, off, 64);
    uneq_sum += __shfl_down(uneq_sum, off, 64);
    valid    += __shfl_down(valid, off, 64);
  }

  __syncthreads();  // all mask lookups done -> safe to reuse sbm as floats
  float* sf = (float*)sbm;
  if (lane == 0) {
    sf[wv * 3 + 0] = eq_sum;
    sf[wv * 3 + 1] = uneq_sum;
    sf[wv * 3 + 2] = valid;
  }
  __syncthreads();
  if (t == 0) {
    float e = 0.0f, u = 0.0f, v = 0.0f;
    #pragma unroll
    for (int w = 0; w < THREADS / 64; ++w) {
      e += sf[w * 3 + 0];
      u += sf[w * 3 + 1];
      v += sf[w * 3 + 2];
    }
    float* slot = slots + 3 * bid;
    slot[0] = e;
    slot[1] = u;
    slot[2] = v;
  }

  cg::this_grid().sync();

  // ---- Phase C: block 0 reduces all slots and writes the scalar ----
  if (bid == 0) {
    float e = 0.0f, u = 0.0f, v = 0.0f;
    for (int s = t; s < nblocks; s += THREADS) {
      e += slots[3 * s + 0];
      u += slots[3 * s + 1];
      v += slots[3 * s + 2];
    }
    #pragma unroll
    for (int off = 32; off > 0; off >>= 1) {
      e += __shfl_down(e, off, 64);
      u += __shfl_down(u, off, 64);
      v += __shfl_down(v, off, 64);
    }
    __syncthreads();  // reuse sf again
    if (lane == 0) {
      sf[wv * 3 + 0] = e;
      sf[wv * 3 + 1] = u;
      sf[wv * 3 + 2] = v;
    }
    __syncthreads();
    if (t == 0) {
      float te = 0.0f, tu = 0.0f, tv = 0.0f;
      #pragma unroll
      for (int w = 0; w < THREADS / 64; ++w) {
        te += sf[w * 3 + 0];
        tu += sf[w * 3 + 1];
        tv += sf[w * 3 + 2];
      }
      out[0] = (te + tu) / (tv + EPS_F);  // ALPHA=1, LOSS_WEIGHT=1
    }
  }
}

extern "C" void kernel_launch(void* const* d_in, const int* in_sizes, int n_in,
                              void* d_out, int out_size, void* d_ws,
                              size_t ws_size, hipStream_t stream) {
  const float* pred = (const float*)d_in[0];
  const float* targ = (const float*)d_in[1];
  const void* mask = d_in[2];  // bool array; layout detected on device
  const int* idxA = (const int*)d_in[3];
  const int* idxB = (const int*)d_in[4];
  float* out = (float*)d_out;
  float* slots = (float*)d_ws;
  unsigned long long* mpack64 =
      (unsigned long long*)((char*)d_ws + PK_OFF_BYTES);

  int total = in_sizes[3];                 // N * SAMPLE_NUM = 160000
  const int rows = total / SAMPLE_NUM;     // 32

  void* args[] = {(void*)&pred, (void*)&targ,  (void*)&mask,
                  (void*)&idxA, (void*)&idxB,  (void*)&mpack64,
                  (void*)&slots, (void*)&out,  (void*)&total};
  dim3 grid(rows * VBLK_PER_ROW);  // 256 blocks: co-resident on 256 CUs
  dim3 block(THREADS);
  hipLaunchCooperativeKernel((const void*)ranking_loss_fused, grid, block,
                             args, 0, stream);
}